// Round 7
// baseline (175.893 us; speedup 1.0000x reference)
//
#include <hip/hip_runtime.h>
#include <hip/hip_bf16.h>

#define NH 64

typedef _Float16 half8 __attribute__((ext_vector_type(8)));
typedef float float4v __attribute__((ext_vector_type(4)));

__device__ __forceinline__ float fast_tanh(float x) {
  float ax = fabsf(x);
  float e  = __expf(-2.0f * ax);
  float y  = (1.0f - e) * __builtin_amdgcn_rcpf(1.0f + e);
  return copysignf(y, x);
}

// B_k[h][j] = mono_k(h) * W2[h][j], packed in MFMA B-fragment lane order for
// v_mfma_f32_16x16x32_f16:  B[k_in=quad*8+jj + 32*ks][n=col],  lane=quad*16+col.
// Slot layout (half units): frag(slot,nt,ks) at ((slot*4+nt)*2+ks)*512 + lane*8 + jj.
// Slots 0..9 = hi parts of the 10 kinds; slot 10 = lo part of kind 0 (z0 only —
// kinds 1..2 run single-f16, R7: saves 32 MFMAs + 16 loads/tile, error ~5e-4 rel).
// Kinds: 0:z0(y)  1:zp(f1*a) 2:zt(f1*b) 3:zpp(f2*a^2) 4:zpt(f2*ab) 5:ztt(f2*b^2)
//        6:zppp(f3*a^3) 7:zppt(f3*a^2b) 8:zptt(f3*ab^2) 9:zttt(f3*b^3)
// The -2 of tanh'' is folded into kinds 3..5 (A-side supplies f2a = y*f1).
__global__ void prep_B(const float* __restrict__ W1, const float* __restrict__ W2,
                       _Float16* __restrict__ ws) {
  int idx = blockIdx.x * 256 + threadIdx.x;
  if (idx >= NH * NH) return;
  int h = idx >> 6, j = idx & 63;
  float a = W1[h], b = W1[NH + h];
  float w2 = W2[h * NH + j];
  float mono[10] = {1.0f, a, b, -2.0f * a * a, -2.0f * a * b, -2.0f * b * b,
                    a * a * a, a * a * b, a * b * b, b * b * b};
  int ks = h >> 5, quad = (h >> 3) & 3, jj = h & 7;
  int nt = j >> 4, col = j & 15;
  int lane = quad * 16 + col;
#pragma unroll
  for (int s = 0; s < 10; ++s) {
    float v = mono[s] * w2;
    _Float16 hi = (_Float16)v;
    ws[((s * 4 + nt) * 2 + ks) * 512 + lane * 8 + jj] = hi;
    if (s == 0) {
      _Float16 lo = (_Float16)(v - (float)hi);
      ws[((10 * 4 + nt) * 2 + ks) * 512 + lane * 8 + jj] = lo;
    }
  }
}

__device__ __forceinline__ half8 ldB(const _Float16* ws, int slot, int nt, int ks, int lane) {
  return *(const half8*)(ws + ((slot * 4 + nt) * 2 + ks) * 512 + lane * 8);
}

// 256 threads = 4 waves; wave w handles point-tile blockIdx*4+w (16 points).
// MFMA 16x16x32 f16: M=16 points, N=64 j (4 ntiles), K=64 h (2 ksteps).
// hi/lo f16 split (3 MFMAs) on kind 0 only; single-f16 on kinds 1..9.
// waves_per_eu(4,4): R6 ran 2/EU (Occ 17.6%) and was latency-bound
// (MfmaUtil 11.6, VALU 43). VGPR fit exactly 128 = the 4/EU budget.
__global__ __launch_bounds__(256) __attribute__((amdgpu_waves_per_eu(4, 4)))
void pinn_mfma(
    const float* __restrict__ phi, const float* __restrict__ theta,
    const float* __restrict__ radius, const float* __restrict__ hth,
    const float* __restrict__ hph, const float* __restrict__ br,
    const float* __restrict__ W1, const float* __restrict__ b1,
    const float* __restrict__ b2, const float* __restrict__ W3,
    const _Float16* __restrict__ Bws, float* __restrict__ out, int n) {
  const int lane = threadIdx.x & 63;
  const int wave = threadIdx.x >> 6;
  const int tile = blockIdx.x * 4 + wave;
  const int quad = lane >> 4, col = lane & 15;
  const int pbase = tile * 16;
  if (pbase >= n) return;

  // ---- A-fragment generation: lane's point m=col, h = 32*ks + quad*8 + jj ----
  float p = phi[pbase + col], t = theta[pbase + col];
  half8 aYh[2], aYl[2], aF1[2], aF2[2], aF3[2];
#pragma unroll
  for (int ks = 0; ks < 2; ++ks) {
#pragma unroll
    for (int jj = 0; jj < 8; ++jj) {
      int h = ks * 32 + quad * 8 + jj;
      float z = fmaf(p, W1[h], fmaf(t, W1[NH + h], b1[h]));
      float y = fast_tanh(z);
      float f1 = fmaf(-y, y, 1.0f);
      float f2a = y * f1;                       // true f2 = -2*y*f1; -2 folded into B
      float f3 = f1 * fmaf(-6.0f, f1, 4.0f);
      _Float16 yh = (_Float16)y;
      aYh[ks][jj] = yh;   aYl[ks][jj] = (_Float16)(y - (float)yh);
      aF1[ks][jj] = (_Float16)f1;
      aF2[ks][jj] = (_Float16)f2a;
      aF3[ks][jj] = (_Float16)f3;
    }
  }

  float4v Tacc[9];
#pragma unroll
  for (int x = 0; x < 9; ++x) Tacc[x] = (float4v){0.f, 0.f, 0.f, 0.f};

#pragma unroll
  for (int nt = 0; nt < 4; ++nt) {
    float4v acc[10];
#pragma unroll
    for (int k = 0; k < 10; ++k) acc[k] = (float4v){0.f, 0.f, 0.f, 0.f};
#pragma unroll
    for (int ks = 0; ks < 2; ++ks) {
      // kind 0 (z0) with full hi/lo split
      half8 b0 = ldB(Bws, 0, nt, ks, lane);
      acc[0] = __builtin_amdgcn_mfma_f32_16x16x32_f16(aYh[ks], b0, acc[0], 0, 0, 0);
      acc[0] = __builtin_amdgcn_mfma_f32_16x16x32_f16(aYl[ks], b0, acc[0], 0, 0, 0);
      half8 b0l = ldB(Bws, 10, nt, ks, lane);
      acc[0] = __builtin_amdgcn_mfma_f32_16x16x32_f16(aYh[ks], b0l, acc[0], 0, 0, 0);
#pragma unroll
      for (int k = 1; k < 10; ++k) {
        half8 ah = (k < 3) ? aF1[ks] : (k < 6) ? aF2[ks] : aF3[ks];
        half8 bh = ldB(Bws, k, nt, ks, lane);
        acc[k] = __builtin_amdgcn_mfma_f32_16x16x32_f16(ah, bh, acc[k], 0, 0, 0);
      }
    }
    // ---- Faa di Bruno + W3 on C-layout: lane holds (point=quad*4+r, j=nt*16+col) ----
    float b2v = b2[nt * 16 + col];
    float w3v = W3[nt * 16 + col];
#pragma unroll
    for (int r = 0; r < 4; ++r) {
      float z0 = acc[0][r] + b2v;
      float y2 = fast_tanh(z0);
      float g1 = fmaf(-y2, y2, 1.0f);
      float g2 = -2.0f * (y2 * g1);
      float g3 = g1 * fmaf(-6.0f, g1, 4.0f);
      float gp = acc[1][r], gt = acc[2][r];
      float gpp = acc[3][r], gpt = acc[4][r], gtt = acc[5][r];
      float zppp = acc[6][r], zppt = acc[7][r], zptt = acc[8][r], zttt = acc[9][r];
      float gp2 = gp * gp, gt2 = gt * gt;
      Tacc[0][r] = fmaf(w3v, g1 * gp, Tacc[0][r]);
      Tacc[1][r] = fmaf(w3v, g1 * gt, Tacc[1][r]);
      Tacc[2][r] = fmaf(w3v, fmaf(g2, gp2, g1 * gpp), Tacc[2][r]);
      Tacc[3][r] = fmaf(w3v, fmaf(g2, gp * gt, g1 * gpt), Tacc[3][r]);
      Tacc[4][r] = fmaf(w3v, fmaf(g2, gt2, g1 * gtt), Tacc[4][r]);
      Tacc[5][r] = fmaf(w3v, fmaf(g3, gp2 * gp, fmaf(3.0f * g2, gp * gpp, g1 * zppp)), Tacc[5][r]);
      Tacc[6][r] = fmaf(w3v, fmaf(g3, gp2 * gt, fmaf(g2, fmaf(2.0f, gp * gpt, gt * gpp), g1 * zppt)), Tacc[6][r]);
      Tacc[7][r] = fmaf(w3v, fmaf(g3, gp * gt2, fmaf(g2, fmaf(2.0f, gt * gpt, gp * gtt), g1 * zptt)), Tacc[7][r]);
      Tacc[8][r] = fmaf(w3v, fmaf(g3, gt2 * gt, fmaf(3.0f * g2, gt * gtt, g1 * zttt)), Tacc[8][r]);
    }
  }

  // ---- reduce over j: butterfly across the 16 cols (same quad group) ----
#pragma unroll
  for (int x = 0; x < 9; ++x) {
#pragma unroll
    for (int r = 0; r < 4; ++r) {
      float v = Tacc[x][r];
      v += __shfl_xor(v, 1, 16);
      v += __shfl_xor(v, 2, 16);
      v += __shfl_xor(v, 4, 16);
      v += __shfl_xor(v, 8, 16);
      Tacc[x][r] = v;
    }
  }

  // lane handles point = quad*4 + (col&3); lanes col<4 store.
  int rsel = col & 3;
  float T[9];
#pragma unroll
  for (int x = 0; x < 9; ++x) {
    float4v v = Tacc[x];
    T[x] = (rsel == 0) ? v[0] : (rsel == 1) ? v[1] : (rsel == 2) ? v[2] : v[3];
  }
  float Tp = T[0], Tt = T[1], Tpp = T[2], Tpt = T[3], Ttt = T[4];
  float Tppp = T[5], Tppt = T[6], Tptt = T[7], Tttt = T[8];

  int pi = pbase + quad * 4 + rsel;
  float t2 = theta[pi];
  float s = sinf(t2), c = cosf(t2);
  float inv_s = 1.0f / s;
  float inv_s2 = inv_s * inv_s;

  float A = Tp * inv_s + Tt;          // u_theta
  float D = Tp * inv_s - Tt;          // u_phi
  float q1 = Tpt * inv_s - Tp * c * inv_s2;
  float A_t = q1 + Ttt;
  float D_t = q1 - Ttt;
  float q2 = Tptt * inv_s - 2.0f * Tpt * c * inv_s2
           + Tp * (s * s + 2.0f * c * c) * inv_s2 * inv_s;
  float A_tt = q2 + Tttt;
  float D_tt = q2 - Tttt;
  float A_pp = Tppp * inv_s + Tppt;
  float D_p  = Tpp * inv_s - Tpt;
  float D_pp = Tppp * inv_s - Tppt;

  float utt   = -(A_t * s + A * c);
  float uttt  = -(A_tt * s + 2.0f * A_t * c - A * s) * s + utt * c;
  float utpp  = -A_pp;
  float upht  = D_t * s + D * c;
  float uphtt = (D_tt * s + 2.0f * D_t * c - D * s) * s + upht * c;
  float upp   = D_p;
  float uppp  = D_pp;

  float r = radius[pi];
  float inv_r = 1.0f / r;
  float inv_r2 = inv_r * inv_r;
  float div_uh = (utt + upp) * inv_r * inv_s;
  float lap_t = s * inv_r2 * uttt + utpp * inv_s2 * inv_r2;
  float lap_p = s * inv_r2 * uphtt + uppp * inv_s2 * inv_r2;
  float comp = s * (lap_t * lap_t + lap_p * lap_p);
  float sv = -(A * hth[pi] + D * hph[pi]) - br[pi] * div_uh;
  float tg = div_uh - A * (s / c) * inv_r;

  if (col < 4) {
    out[pi]         = A;
    out[n + pi]     = D;
    out[2 * n + pi] = div_uh;
    out[3 * n + pi] = sv;
    out[4 * n + pi] = tg;
    out[5 * n + pi] = comp;
  }
}

extern "C" void kernel_launch(void* const* d_in, const int* in_sizes, int n_in,
                              void* d_out, int out_size, void* d_ws, size_t ws_size,
                              hipStream_t stream) {
  const float* phi    = (const float*)d_in[0];
  const float* theta  = (const float*)d_in[1];
  const float* radius = (const float*)d_in[2];
  const float* hth    = (const float*)d_in[3];
  const float* hph    = (const float*)d_in[4];
  const float* br     = (const float*)d_in[5];
  const float* W1     = (const float*)d_in[6];
  const float* b1     = (const float*)d_in[7];
  const float* W2     = (const float*)d_in[8];
  const float* b2     = (const float*)d_in[9];
  const float* W3     = (const float*)d_in[10];
  (void)ws_size; (void)n_in; (void)out_size;

  _Float16* Bws = (_Float16*)d_ws;     // 11 slots * 4 nt * 2 ks * 512 halfs = 88 KB
  float* out = (float*)d_out;
  int n = in_sizes[0];

  prep_B<<<(NH * NH + 255) / 256, 256, 0, stream>>>(W1, W2, Bws);
  int ntiles = (n + 15) / 16;
  int nblocks = (ntiles + 3) / 4;
  pinn_mfma<<<nblocks, 256, 0, stream>>>(
      phi, theta, radius, hth, hph, br, W1, b1, b2, W3, Bws, out, n);
}

// Round 8
// 145.925 us; speedup vs baseline: 1.2054x; 1.2054x over previous
//
#include <hip/hip_runtime.h>
#include <hip/hip_bf16.h>

#define NH 64

typedef _Float16 half8 __attribute__((ext_vector_type(8)));
typedef float float4v __attribute__((ext_vector_type(4)));

__device__ __forceinline__ float fast_tanh(float x) {
  float ax = fabsf(x);
  float e  = __expf(-2.0f * ax);
  float y  = (1.0f - e) * __builtin_amdgcn_rcpf(1.0f + e);
  return copysignf(y, x);
}

// B_k[h][j] = mono_k(h) * W2[h][j], packed in MFMA B-fragment lane order for
// v_mfma_f32_16x16x32_f16:  B[k_in=quad*8+jj + 32*ks][n=col],  lane=quad*16+col.
// Slot layout (half units): frag(slot,nt,ks) at ((slot*4+nt)*2+ks)*512 + lane*8 + jj.
// Slots 0..9 = hi parts of the 10 kinds; slot 10 = lo part of kind 0 (z0 only).
// Kinds: 0:z0(y)  1:zp(f1*a) 2:zt(f1*b) 3:zpp(f2*a^2) 4:zpt(f2*ab) 5:ztt(f2*b^2)
//        6:zppp(f3*a^3) 7:zppt(f3*a^2b) 8:zptt(f3*ab^2) 9:zttt(f3*b^3)
// The -2 of tanh'' is folded into kinds 3..5 (A-side supplies f2a = y*f1).
__global__ void prep_B(const float* __restrict__ W1, const float* __restrict__ W2,
                       _Float16* __restrict__ ws) {
  int idx = blockIdx.x * 256 + threadIdx.x;
  if (idx >= NH * NH) return;
  int h = idx >> 6, j = idx & 63;
  float a = W1[h], b = W1[NH + h];
  float w2 = W2[h * NH + j];
  float mono[10] = {1.0f, a, b, -2.0f * a * a, -2.0f * a * b, -2.0f * b * b,
                    a * a * a, a * a * b, a * b * b, b * b * b};
  int ks = h >> 5, quad = (h >> 3) & 3, jj = h & 7;
  int nt = j >> 4, col = j & 15;
  int lane = quad * 16 + col;
#pragma unroll
  for (int s = 0; s < 10; ++s) {
    float v = mono[s] * w2;
    _Float16 hi = (_Float16)v;
    ws[((s * 4 + nt) * 2 + ks) * 512 + lane * 8 + jj] = hi;
    if (s == 0) {
      _Float16 lo = (_Float16)(v - (float)hi);
      ws[((10 * 4 + nt) * 2 + ks) * 512 + lane * 8 + jj] = lo;
    }
  }
}

__device__ __forceinline__ half8 ldB(const _Float16* ws, int slot, int nt, int ks, int lane) {
  return *(const half8*)(ws + ((slot * 4 + nt) * 2 + ks) * 512 + lane * 8);
}

// 256 threads = 4 waves; wave w handles point-tile blockIdx*4+w (16 points).
// MFMA 16x16x32 f16: M=16 points, N=64 j (4 ntiles), K=64 h (2 ksteps).
// hi/lo f16 split (3 MFMAs) on kind 0 only; single-f16 on kinds 1..9.
// waves_per_eu(3,3): gfx950 unified VGPR+AGPR file — the ~150-reg working set
// (40 A-frag + 40 MFMA acc + 36 Tacc + temps) fits the 3-waves/EU budget (~170)
// but NOT the 4-waves budget (128): R7's (4,4) spilled 187 MB to scratch.
__global__ __launch_bounds__(256) __attribute__((amdgpu_waves_per_eu(3, 3)))
void pinn_mfma(
    const float* __restrict__ phi, const float* __restrict__ theta,
    const float* __restrict__ radius, const float* __restrict__ hth,
    const float* __restrict__ hph, const float* __restrict__ br,
    const float* __restrict__ W1, const float* __restrict__ b1,
    const float* __restrict__ b2, const float* __restrict__ W3,
    const _Float16* __restrict__ Bws, float* __restrict__ out, int n) {
  const int lane = threadIdx.x & 63;
  const int wave = threadIdx.x >> 6;
  const int tile = blockIdx.x * 4 + wave;
  const int quad = lane >> 4, col = lane & 15;
  const int pbase = tile * 16;
  if (pbase >= n) return;

  // ---- A-fragment generation: lane's point m=col, h = 32*ks + quad*8 + jj ----
  float p = phi[pbase + col], t = theta[pbase + col];
  half8 aYh[2], aYl[2], aF1[2], aF2[2], aF3[2];
#pragma unroll
  for (int ks = 0; ks < 2; ++ks) {
#pragma unroll
    for (int jj = 0; jj < 8; ++jj) {
      int h = ks * 32 + quad * 8 + jj;
      float z = fmaf(p, W1[h], fmaf(t, W1[NH + h], b1[h]));
      float y = fast_tanh(z);
      float f1 = fmaf(-y, y, 1.0f);
      float f2a = y * f1;                       // true f2 = -2*y*f1; -2 folded into B
      float f3 = f1 * fmaf(-6.0f, f1, 4.0f);
      _Float16 yh = (_Float16)y;
      aYh[ks][jj] = yh;   aYl[ks][jj] = (_Float16)(y - (float)yh);
      aF1[ks][jj] = (_Float16)f1;
      aF2[ks][jj] = (_Float16)f2a;
      aF3[ks][jj] = (_Float16)f3;
    }
  }

  float4v Tacc[9];
#pragma unroll
  for (int x = 0; x < 9; ++x) Tacc[x] = (float4v){0.f, 0.f, 0.f, 0.f};

#pragma unroll
  for (int nt = 0; nt < 4; ++nt) {
    float4v acc[10];
#pragma unroll
    for (int k = 0; k < 10; ++k) acc[k] = (float4v){0.f, 0.f, 0.f, 0.f};
#pragma unroll
    for (int ks = 0; ks < 2; ++ks) {
      // kind 0 (z0) with full hi/lo split
      half8 b0 = ldB(Bws, 0, nt, ks, lane);
      acc[0] = __builtin_amdgcn_mfma_f32_16x16x32_f16(aYh[ks], b0, acc[0], 0, 0, 0);
      acc[0] = __builtin_amdgcn_mfma_f32_16x16x32_f16(aYl[ks], b0, acc[0], 0, 0, 0);
      half8 b0l = ldB(Bws, 10, nt, ks, lane);
      acc[0] = __builtin_amdgcn_mfma_f32_16x16x32_f16(aYh[ks], b0l, acc[0], 0, 0, 0);
#pragma unroll
      for (int k = 1; k < 10; ++k) {
        half8 ah = (k < 3) ? aF1[ks] : (k < 6) ? aF2[ks] : aF3[ks];
        half8 bh = ldB(Bws, k, nt, ks, lane);
        acc[k] = __builtin_amdgcn_mfma_f32_16x16x32_f16(ah, bh, acc[k], 0, 0, 0);
      }
    }
    // ---- Faa di Bruno + W3 on C-layout: lane holds (point=quad*4+r, j=nt*16+col) ----
    float b2v = b2[nt * 16 + col];
    float w3v = W3[nt * 16 + col];
#pragma unroll
    for (int r = 0; r < 4; ++r) {
      float z0 = acc[0][r] + b2v;
      float y2 = fast_tanh(z0);
      float g1 = fmaf(-y2, y2, 1.0f);
      float g2 = -2.0f * (y2 * g1);
      float g3 = g1 * fmaf(-6.0f, g1, 4.0f);
      float gp = acc[1][r], gt = acc[2][r];
      float gpp = acc[3][r], gpt = acc[4][r], gtt = acc[5][r];
      float zppp = acc[6][r], zppt = acc[7][r], zptt = acc[8][r], zttt = acc[9][r];
      float gp2 = gp * gp, gt2 = gt * gt;
      Tacc[0][r] = fmaf(w3v, g1 * gp, Tacc[0][r]);
      Tacc[1][r] = fmaf(w3v, g1 * gt, Tacc[1][r]);
      Tacc[2][r] = fmaf(w3v, fmaf(g2, gp2, g1 * gpp), Tacc[2][r]);
      Tacc[3][r] = fmaf(w3v, fmaf(g2, gp * gt, g1 * gpt), Tacc[3][r]);
      Tacc[4][r] = fmaf(w3v, fmaf(g2, gt2, g1 * gtt), Tacc[4][r]);
      Tacc[5][r] = fmaf(w3v, fmaf(g3, gp2 * gp, fmaf(3.0f * g2, gp * gpp, g1 * zppp)), Tacc[5][r]);
      Tacc[6][r] = fmaf(w3v, fmaf(g3, gp2 * gt, fmaf(g2, fmaf(2.0f, gp * gpt, gt * gpp), g1 * zppt)), Tacc[6][r]);
      Tacc[7][r] = fmaf(w3v, fmaf(g3, gp * gt2, fmaf(g2, fmaf(2.0f, gt * gpt, gp * gtt), g1 * zptt)), Tacc[7][r]);
      Tacc[8][r] = fmaf(w3v, fmaf(g3, gt2 * gt, fmaf(3.0f * g2, gt * gtt, g1 * zttt)), Tacc[8][r]);
    }
  }

  // ---- reduce over j: butterfly across the 16 cols (same quad group) ----
#pragma unroll
  for (int x = 0; x < 9; ++x) {
#pragma unroll
    for (int r = 0; r < 4; ++r) {
      float v = Tacc[x][r];
      v += __shfl_xor(v, 1, 16);
      v += __shfl_xor(v, 2, 16);
      v += __shfl_xor(v, 4, 16);
      v += __shfl_xor(v, 8, 16);
      Tacc[x][r] = v;
    }
  }

  // lane handles point = quad*4 + (col&3); lanes col<4 store.
  int rsel = col & 3;
  float T[9];
#pragma unroll
  for (int x = 0; x < 9; ++x) {
    float4v v = Tacc[x];
    T[x] = (rsel == 0) ? v[0] : (rsel == 1) ? v[1] : (rsel == 2) ? v[2] : v[3];
  }
  float Tp = T[0], Tt = T[1], Tpp = T[2], Tpt = T[3], Ttt = T[4];
  float Tppp = T[5], Tppt = T[6], Tptt = T[7], Tttt = T[8];

  int pi = pbase + quad * 4 + rsel;
  float t2 = theta[pi];
  float s = sinf(t2), c = cosf(t2);
  float inv_s = 1.0f / s;
  float inv_s2 = inv_s * inv_s;

  float A = Tp * inv_s + Tt;          // u_theta
  float D = Tp * inv_s - Tt;          // u_phi
  float q1 = Tpt * inv_s - Tp * c * inv_s2;
  float A_t = q1 + Ttt;
  float D_t = q1 - Ttt;
  float q2 = Tptt * inv_s - 2.0f * Tpt * c * inv_s2
           + Tp * (s * s + 2.0f * c * c) * inv_s2 * inv_s;
  float A_tt = q2 + Tttt;
  float D_tt = q2 - Tttt;
  float A_pp = Tppp * inv_s + Tppt;
  float D_p  = Tpp * inv_s - Tpt;
  float D_pp = Tppp * inv_s - Tppt;

  float utt   = -(A_t * s + A * c);
  float uttt  = -(A_tt * s + 2.0f * A_t * c - A * s) * s + utt * c;
  float utpp  = -A_pp;
  float upht  = D_t * s + D * c;
  float uphtt = (D_tt * s + 2.0f * D_t * c - D * s) * s + upht * c;
  float upp   = D_p;
  float uppp  = D_pp;

  float r = radius[pi];
  float inv_r = 1.0f / r;
  float inv_r2 = inv_r * inv_r;
  float div_uh = (utt + upp) * inv_r * inv_s;
  float lap_t = s * inv_r2 * uttt + utpp * inv_s2 * inv_r2;
  float lap_p = s * inv_r2 * uphtt + uppp * inv_s2 * inv_r2;
  float comp = s * (lap_t * lap_t + lap_p * lap_p);
  float sv = -(A * hth[pi] + D * hph[pi]) - br[pi] * div_uh;
  float tg = div_uh - A * (s / c) * inv_r;

  if (col < 4) {
    out[pi]         = A;
    out[n + pi]     = D;
    out[2 * n + pi] = div_uh;
    out[3 * n + pi] = sv;
    out[4 * n + pi] = tg;
    out[5 * n + pi] = comp;
  }
}

extern "C" void kernel_launch(void* const* d_in, const int* in_sizes, int n_in,
                              void* d_out, int out_size, void* d_ws, size_t ws_size,
                              hipStream_t stream) {
  const float* phi    = (const float*)d_in[0];
  const float* theta  = (const float*)d_in[1];
  const float* radius = (const float*)d_in[2];
  const float* hth    = (const float*)d_in[3];
  const float* hph    = (const float*)d_in[4];
  const float* br     = (const float*)d_in[5];
  const float* W1     = (const float*)d_in[6];
  const float* b1     = (const float*)d_in[7];
  const float* W2     = (const float*)d_in[8];
  const float* b2     = (const float*)d_in[9];
  const float* W3     = (const float*)d_in[10];
  (void)ws_size; (void)n_in; (void)out_size;

  _Float16* Bws = (_Float16*)d_ws;     // 11 slots * 4 nt * 2 ks * 512 halfs = 88 KB
  float* out = (float*)d_out;
  int n = in_sizes[0];

  prep_B<<<(NH * NH + 255) / 256, 256, 0, stream>>>(W1, W2, Bws);
  int ntiles = (n + 15) / 16;
  int nblocks = (ntiles + 3) / 4;
  pinn_mfma<<<nblocks, 256, 0, stream>>>(
      phi, theta, radius, hth, hph, br, W1, b1, b2, W3, Bws, out, n);
}

// Round 9
// 140.666 us; speedup vs baseline: 1.2504x; 1.0374x over previous
//
#include <hip/hip_runtime.h>
#include <hip/hip_bf16.h>

#define NH 64

typedef _Float16 half8 __attribute__((ext_vector_type(8)));
typedef float float4v __attribute__((ext_vector_type(4)));

__device__ __forceinline__ float fast_tanh(float x) {
  float ax = fabsf(x);
  float e  = __expf(-2.0f * ax);
  float y  = (1.0f - e) * __builtin_amdgcn_rcpf(1.0f + e);
  return copysignf(y, x);
}

// B_k[h][j] = mono_k(h) * W2[h][j], packed in MFMA B-fragment lane order for
// v_mfma_f32_16x16x32_f16:  B[k_in=quad*8+jj + 32*ks][n=col],  lane=quad*16+col.
// Slot layout (half units): frag(slot,nt,ks) at ((slot*4+nt)*2+ks)*512 + lane*8 + jj.
// Slots 0..9 = hi parts of the 10 kinds; slot 10 = lo part of kind 0 (z0 only).
// Kinds: 0:z0(y)  1:zp(f1*a) 2:zt(f1*b) 3:zpp(f2*a^2) 4:zpt(f2*ab) 5:ztt(f2*b^2)
//        6:zppp(f3*a^3) 7:zppt(f3*a^2b) 8:zptt(f3*ab^2) 9:zttt(f3*b^3)
// The -2 of tanh'' is folded into kinds 3..5 (A-side supplies f2a = y*f1).
__global__ void prep_B(const float* __restrict__ W1, const float* __restrict__ W2,
                       _Float16* __restrict__ ws) {
  int idx = blockIdx.x * 256 + threadIdx.x;
  if (idx >= NH * NH) return;
  int h = idx >> 6, j = idx & 63;
  float a = W1[h], b = W1[NH + h];
  float w2 = W2[h * NH + j];
  float mono[10] = {1.0f, a, b, -2.0f * a * a, -2.0f * a * b, -2.0f * b * b,
                    a * a * a, a * a * b, a * b * b, b * b * b};
  int ks = h >> 5, quad = (h >> 3) & 3, jj = h & 7;
  int nt = j >> 4, col = j & 15;
  int lane = quad * 16 + col;
#pragma unroll
  for (int s = 0; s < 10; ++s) {
    float v = mono[s] * w2;
    _Float16 hi = (_Float16)v;
    ws[((s * 4 + nt) * 2 + ks) * 512 + lane * 8 + jj] = hi;
    if (s == 0) {
      _Float16 lo = (_Float16)(v - (float)hi);
      ws[((10 * 4 + nt) * 2 + ks) * 512 + lane * 8 + jj] = lo;
    }
  }
}

__device__ __forceinline__ half8 ldB(const _Float16* ws, int slot, int nt, int ks, int lane) {
  return *(const half8*)(ws + ((slot * 4 + nt) * 2 + ks) * 512 + lane * 8);
}

// 256 threads = 4 waves; wave w handles point-tile blockIdx*4+w (16 points).
// MFMA 16x16x32 f16: M=16 points, N=64 j (4 ntiles), K=64 h (2 ksteps).
// hi/lo f16 split on kind 0 only; single-f16 on kinds 1..9.
// R9: A-fragments staged in LDS (wave-private, no barrier) instead of 40 live
// VGPRs across the nt-loop — R8's (3,3) spilled 46 MB because the arch-side
// register partition (~84) couldn't hold A-frags + temps. Now arch ~60.
__global__ __launch_bounds__(256) __attribute__((amdgpu_waves_per_eu(3, 3)))
void pinn_mfma(
    const float* __restrict__ phi, const float* __restrict__ theta,
    const float* __restrict__ radius, const float* __restrict__ hth,
    const float* __restrict__ hph, const float* __restrict__ br,
    const float* __restrict__ W1, const float* __restrict__ b1,
    const float* __restrict__ b2, const float* __restrict__ W3,
    const _Float16* __restrict__ Bws, float* __restrict__ out, int n) {
  // afrag[wave][kind*2+ks][lane][8]: kinds {0:Yh 1:Yl 2:F1 3:F2 4:F3}
  __shared__ _Float16 afrag[4][10][64][8];   // 40 KB
  const int lane = threadIdx.x & 63;
  const int wave = threadIdx.x >> 6;
  const int tile = blockIdx.x * 4 + wave;
  const int quad = lane >> 4, col = lane & 15;
  const int pbase = tile * 16;
  if (pbase >= n) return;

  // ---- A-fragment generation: lane's point m=col, h = 32*ks + quad*8 + jj ----
  float p = phi[pbase + col], t = theta[pbase + col];
#pragma unroll
  for (int ks = 0; ks < 2; ++ks) {
    half8 vYh, vYl, vF1, vF2, vF3;
#pragma unroll
    for (int jj = 0; jj < 8; ++jj) {
      int h = ks * 32 + quad * 8 + jj;
      float z = fmaf(p, W1[h], fmaf(t, W1[NH + h], b1[h]));
      float y = fast_tanh(z);
      float f1 = fmaf(-y, y, 1.0f);
      float f2a = y * f1;                       // true f2 = -2*y*f1; -2 folded into B
      float f3 = f1 * fmaf(-6.0f, f1, 4.0f);
      _Float16 yh = (_Float16)y;
      vYh[jj] = yh;   vYl[jj] = (_Float16)(y - (float)yh);
      vF1[jj] = (_Float16)f1;
      vF2[jj] = (_Float16)f2a;
      vF3[jj] = (_Float16)f3;
    }
    *(half8*)&afrag[wave][0 * 2 + ks][lane][0] = vYh;
    *(half8*)&afrag[wave][1 * 2 + ks][lane][0] = vYl;
    *(half8*)&afrag[wave][2 * 2 + ks][lane][0] = vF1;
    *(half8*)&afrag[wave][3 * 2 + ks][lane][0] = vF2;
    *(half8*)&afrag[wave][4 * 2 + ks][lane][0] = vF3;
  }

  float4v Tacc[9];
#pragma unroll
  for (int x = 0; x < 9; ++x) Tacc[x] = (float4v){0.f, 0.f, 0.f, 0.f};

#pragma unroll
  for (int nt = 0; nt < 4; ++nt) {
    float4v acc[10];
#pragma unroll
    for (int k = 0; k < 10; ++k) acc[k] = (float4v){0.f, 0.f, 0.f, 0.f};
#pragma unroll
    for (int ks = 0; ks < 2; ++ks) {
      half8 aYh = *(const half8*)&afrag[wave][0 * 2 + ks][lane][0];
      half8 aYl = *(const half8*)&afrag[wave][1 * 2 + ks][lane][0];
      half8 aF1 = *(const half8*)&afrag[wave][2 * 2 + ks][lane][0];
      half8 aF2 = *(const half8*)&afrag[wave][3 * 2 + ks][lane][0];
      half8 aF3 = *(const half8*)&afrag[wave][4 * 2 + ks][lane][0];
      // kind 0 (z0) with full hi/lo split
      half8 b0 = ldB(Bws, 0, nt, ks, lane);
      acc[0] = __builtin_amdgcn_mfma_f32_16x16x32_f16(aYh, b0, acc[0], 0, 0, 0);
      acc[0] = __builtin_amdgcn_mfma_f32_16x16x32_f16(aYl, b0, acc[0], 0, 0, 0);
      half8 b0l = ldB(Bws, 10, nt, ks, lane);
      acc[0] = __builtin_amdgcn_mfma_f32_16x16x32_f16(aYh, b0l, acc[0], 0, 0, 0);
#pragma unroll
      for (int k = 1; k < 10; ++k) {
        half8 ah = (k < 3) ? aF1 : (k < 6) ? aF2 : aF3;
        half8 bh = ldB(Bws, k, nt, ks, lane);
        acc[k] = __builtin_amdgcn_mfma_f32_16x16x32_f16(ah, bh, acc[k], 0, 0, 0);
      }
    }
    // ---- Faa di Bruno + W3 on C-layout: lane holds (point=quad*4+r, j=nt*16+col) ----
    float b2v = b2[nt * 16 + col];
    float w3v = W3[nt * 16 + col];
#pragma unroll
    for (int r = 0; r < 4; ++r) {
      float z0 = acc[0][r] + b2v;
      float y2 = fast_tanh(z0);
      float g1 = fmaf(-y2, y2, 1.0f);
      float g2 = -2.0f * (y2 * g1);
      float g3 = g1 * fmaf(-6.0f, g1, 4.0f);
      float gp = acc[1][r], gt = acc[2][r];
      float gpp = acc[3][r], gpt = acc[4][r], gtt = acc[5][r];
      float zppp = acc[6][r], zppt = acc[7][r], zptt = acc[8][r], zttt = acc[9][r];
      float gp2 = gp * gp, gt2 = gt * gt;
      Tacc[0][r] = fmaf(w3v, g1 * gp, Tacc[0][r]);
      Tacc[1][r] = fmaf(w3v, g1 * gt, Tacc[1][r]);
      Tacc[2][r] = fmaf(w3v, fmaf(g2, gp2, g1 * gpp), Tacc[2][r]);
      Tacc[3][r] = fmaf(w3v, fmaf(g2, gp * gt, g1 * gpt), Tacc[3][r]);
      Tacc[4][r] = fmaf(w3v, fmaf(g2, gt2, g1 * gtt), Tacc[4][r]);
      Tacc[5][r] = fmaf(w3v, fmaf(g3, gp2 * gp, fmaf(3.0f * g2, gp * gpp, g1 * zppp)), Tacc[5][r]);
      Tacc[6][r] = fmaf(w3v, fmaf(g3, gp2 * gt, fmaf(g2, fmaf(2.0f, gp * gpt, gt * gpp), g1 * zppt)), Tacc[6][r]);
      Tacc[7][r] = fmaf(w3v, fmaf(g3, gp * gt2, fmaf(g2, fmaf(2.0f, gt * gpt, gp * gtt), g1 * zptt)), Tacc[7][r]);
      Tacc[8][r] = fmaf(w3v, fmaf(g3, gt2 * gt, fmaf(3.0f * g2, gt * gtt, g1 * zttt)), Tacc[8][r]);
    }
  }

  // ---- reduce over j: butterfly across the 16 cols (same quad group) ----
#pragma unroll
  for (int x = 0; x < 9; ++x) {
#pragma unroll
    for (int r = 0; r < 4; ++r) {
      float v = Tacc[x][r];
      v += __shfl_xor(v, 1, 16);
      v += __shfl_xor(v, 2, 16);
      v += __shfl_xor(v, 4, 16);
      v += __shfl_xor(v, 8, 16);
      Tacc[x][r] = v;
    }
  }

  // lane handles point = quad*4 + (col&3); lanes col<4 store.
  int rsel = col & 3;
  float T[9];
#pragma unroll
  for (int x = 0; x < 9; ++x) {
    float4v v = Tacc[x];
    T[x] = (rsel == 0) ? v[0] : (rsel == 1) ? v[1] : (rsel == 2) ? v[2] : v[3];
  }
  float Tp = T[0], Tt = T[1], Tpp = T[2], Tpt = T[3], Ttt = T[4];
  float Tppp = T[5], Tppt = T[6], Tptt = T[7], Tttt = T[8];

  int pi = pbase + quad * 4 + rsel;
  float t2 = theta[pi];
  float s = sinf(t2), c = cosf(t2);
  float inv_s = 1.0f / s;
  float inv_s2 = inv_s * inv_s;

  float A = Tp * inv_s + Tt;          // u_theta
  float D = Tp * inv_s - Tt;          // u_phi
  float q1 = Tpt * inv_s - Tp * c * inv_s2;
  float A_t = q1 + Ttt;
  float D_t = q1 - Ttt;
  float q2 = Tptt * inv_s - 2.0f * Tpt * c * inv_s2
           + Tp * (s * s + 2.0f * c * c) * inv_s2 * inv_s;
  float A_tt = q2 + Tttt;
  float D_tt = q2 - Tttt;
  float A_pp = Tppp * inv_s + Tppt;
  float D_p  = Tpp * inv_s - Tpt;
  float D_pp = Tppp * inv_s - Tppt;

  float utt   = -(A_t * s + A * c);
  float uttt  = -(A_tt * s + 2.0f * A_t * c - A * s) * s + utt * c;
  float utpp  = -A_pp;
  float upht  = D_t * s + D * c;
  float uphtt = (D_tt * s + 2.0f * D_t * c - D * s) * s + upht * c;
  float upp   = D_p;
  float uppp  = D_pp;

  float r = radius[pi];
  float inv_r = 1.0f / r;
  float inv_r2 = inv_r * inv_r;
  float div_uh = (utt + upp) * inv_r * inv_s;
  float lap_t = s * inv_r2 * uttt + utpp * inv_s2 * inv_r2;
  float lap_p = s * inv_r2 * uphtt + uppp * inv_s2 * inv_r2;
  float comp = s * (lap_t * lap_t + lap_p * lap_p);
  float sv = -(A * hth[pi] + D * hph[pi]) - br[pi] * div_uh;
  float tg = div_uh - A * (s / c) * inv_r;

  if (col < 4) {
    out[pi]         = A;
    out[n + pi]     = D;
    out[2 * n + pi] = div_uh;
    out[3 * n + pi] = sv;
    out[4 * n + pi] = tg;
    out[5 * n + pi] = comp;
  }
}

extern "C" void kernel_launch(void* const* d_in, const int* in_sizes, int n_in,
                              void* d_out, int out_size, void* d_ws, size_t ws_size,
                              hipStream_t stream) {
  const float* phi    = (const float*)d_in[0];
  const float* theta  = (const float*)d_in[1];
  const float* radius = (const float*)d_in[2];
  const float* hth    = (const float*)d_in[3];
  const float* hph    = (const float*)d_in[4];
  const float* br     = (const float*)d_in[5];
  const float* W1     = (const float*)d_in[6];
  const float* b1     = (const float*)d_in[7];
  const float* W2     = (const float*)d_in[8];
  const float* b2     = (const float*)d_in[9];
  const float* W3     = (const float*)d_in[10];
  (void)ws_size; (void)n_in; (void)out_size;

  _Float16* Bws = (_Float16*)d_ws;     // 11 slots * 4 nt * 2 ks * 512 halfs = 88 KB
  float* out = (float*)d_out;
  int n = in_sizes[0];

  prep_B<<<(NH * NH + 255) / 256, 256, 0, stream>>>(W1, W2, Bws);
  int ntiles = (n + 15) / 16;
  int nblocks = (ntiles + 3) / 4;
  pinn_mfma<<<nblocks, 256, 0, stream>>>(
      phi, theta, radius, hth, hph, br, W1, b1, b2, W3, Bws, out, n);
}

// Round 10
// 127.103 us; speedup vs baseline: 1.3839x; 1.1067x over previous
//
#include <hip/hip_runtime.h>
#include <hip/hip_bf16.h>

#define NH 64

typedef _Float16 half8 __attribute__((ext_vector_type(8)));
typedef float float4v __attribute__((ext_vector_type(4)));

__device__ __forceinline__ float fast_tanh(float x) {
  float ax = fabsf(x);
  float e  = __expf(-2.0f * ax);
  float y  = (1.0f - e) * __builtin_amdgcn_rcpf(1.0f + e);
  return copysignf(y, x);
}

// B_k[h][j] = mono_k(h) * W2[h][j], packed in MFMA B-fragment lane order for
// v_mfma_f32_16x16x32_f16:  B[k_in=quad*8+jj + 32*ks][n=col],  lane=quad*16+col.
// Global layout (half units): frag(slot,nt,ks) at ((slot*4+nt)*2+ks)*512 + lane*8 + jj.
// Slots 0..9 = hi parts of the 10 kinds; slot 10 = lo part of kind 0 (z0 only).
// Kinds: 0:z0(y)  1:zp(f1*a) 2:zt(f1*b) 3:zpp(f2*a^2) 4:zpt(f2*ab) 5:ztt(f2*b^2)
//        6:zppp(f3*a^3) 7:zppt(f3*a^2b) 8:zptt(f3*ab^2) 9:zttt(f3*b^3)
// The -2 of tanh'' is folded into kinds 3..5 (A-side supplies f2a = y*f1).
__global__ void prep_B(const float* __restrict__ W1, const float* __restrict__ W2,
                       _Float16* __restrict__ ws) {
  int idx = blockIdx.x * 256 + threadIdx.x;
  if (idx >= NH * NH) return;
  int h = idx >> 6, j = idx & 63;
  float a = W1[h], b = W1[NH + h];
  float w2 = W2[h * NH + j];
  float mono[10] = {1.0f, a, b, -2.0f * a * a, -2.0f * a * b, -2.0f * b * b,
                    a * a * a, a * a * b, a * b * b, b * b * b};
  int ks = h >> 5, quad = (h >> 3) & 3, jj = h & 7;
  int nt = j >> 4, col = j & 15;
  int lane = quad * 16 + col;
#pragma unroll
  for (int s = 0; s < 10; ++s) {
    float v = mono[s] * w2;
    _Float16 hi = (_Float16)v;
    ws[((s * 4 + nt) * 2 + ks) * 512 + lane * 8 + jj] = hi;
    if (s == 0) {
      _Float16 lo = (_Float16)(v - (float)hi);
      ws[((10 * 4 + nt) * 2 + ks) * 512 + lane * 8 + jj] = lo;
    }
  }
}

// 256 threads = 4 waves; wave w handles point-tile blockIdx*4+w (16 points).
// MFMA 16x16x32 f16: M=16 points, N=64 j (4 ntiles), K=64 h (2 ksteps).
// hi/lo f16 split on kind 0 only; single-f16 on kinds 1..9.
// R10: B fragments staged in LDS per nt, DOUBLE-BUFFERED and shared by the
// block's 4 waves (R9 post-mortem: each wave re-reading 88 KB of B from L2
// per tile was the dominant latency source — 720 MB/launch of L2 traffic).
// Regalloc back to (2,2) = 256-reg budget, proven spill-free in R6.
__global__ __launch_bounds__(256) __attribute__((amdgpu_waves_per_eu(2, 2)))
void pinn_mfma(
    const float* __restrict__ phi, const float* __restrict__ theta,
    const float* __restrict__ radius, const float* __restrict__ hth,
    const float* __restrict__ hph, const float* __restrict__ br,
    const float* __restrict__ W1, const float* __restrict__ b1,
    const float* __restrict__ b2, const float* __restrict__ W3,
    const _Float16* __restrict__ Bws, float* __restrict__ out, int n) {
  __shared__ __align__(16) _Float16 bbuf[2][22][512];   // 45 KB: [buf][slot*2+ks][lane*8+jj]
  const int lane = threadIdx.x & 63;
  const int wave = threadIdx.x >> 6;
  const int tile = blockIdx.x * 4 + wave;
  const int quad = lane >> 4, col = lane & 15;
  const int pbase = tile * 16;
  const int pld = min(pbase + col, n - 1);   // clamp; no early return (barriers below)

  // ---- A-fragment generation: lane's point m=col, h = 32*ks + quad*8 + jj ----
  float p = phi[pld], t = theta[pld];
  half8 aYh[2], aYl[2], aF1[2], aF2[2], aF3[2];
#pragma unroll
  for (int ks = 0; ks < 2; ++ks) {
#pragma unroll
    for (int jj = 0; jj < 8; ++jj) {
      int h = ks * 32 + quad * 8 + jj;
      float z = fmaf(p, W1[h], fmaf(t, W1[NH + h], b1[h]));
      float y = fast_tanh(z);
      float f1 = fmaf(-y, y, 1.0f);
      float f2a = y * f1;                       // true f2 = -2*y*f1; -2 folded into B
      float f3 = f1 * fmaf(-6.0f, f1, 4.0f);
      _Float16 yh = (_Float16)y;
      aYh[ks][jj] = yh;   aYl[ks][jj] = (_Float16)(y - (float)yh);
      aF1[ks][jj] = (_Float16)f1;
      aF2[ks][jj] = (_Float16)f2a;
      aF3[ks][jj] = (_Float16)f3;
    }
  }

  // ---- cooperative B staging: wave w owns frags f = w, w+4, w+8, ... (<22) ----
  // frag f = slot*2+ks; global frag offset = (((f>>1)*4 + nt)*2 + (f&1)) * 512.
  half8 pf[6];
  // preload nt=0 into buffer 0
#pragma unroll
  for (int i = 0; i < 6; ++i) {
    int f = wave + 4 * i;
    if (f < 22)
      pf[i] = *(const half8*)(Bws + (((f >> 1) * 4 + 0) * 2 + (f & 1)) * 512 + lane * 8);
  }
#pragma unroll
  for (int i = 0; i < 6; ++i) {
    int f = wave + 4 * i;
    if (f < 22) *(half8*)&bbuf[0][f][lane * 8] = pf[i];
  }
  __syncthreads();

  float4v Tacc[9];
#pragma unroll
  for (int x = 0; x < 9; ++x) Tacc[x] = (float4v){0.f, 0.f, 0.f, 0.f};

#pragma unroll
  for (int nt = 0; nt < 4; ++nt) {
    const int buf = nt & 1;
    // issue global loads for nt+1 (land during compute)
    if (nt < 3) {
#pragma unroll
      for (int i = 0; i < 6; ++i) {
        int f = wave + 4 * i;
        if (f < 22)
          pf[i] = *(const half8*)(Bws + (((f >> 1) * 4 + (nt + 1)) * 2 + (f & 1)) * 512 + lane * 8);
      }
    }

    float4v acc[10];
#pragma unroll
    for (int k = 0; k < 10; ++k) acc[k] = (float4v){0.f, 0.f, 0.f, 0.f};
#pragma unroll
    for (int ks = 0; ks < 2; ++ks) {
      // kind 0 (z0) with full hi/lo split
      half8 b0 = *(const half8*)&bbuf[buf][0 * 2 + ks][lane * 8];
      acc[0] = __builtin_amdgcn_mfma_f32_16x16x32_f16(aYh[ks], b0, acc[0], 0, 0, 0);
      acc[0] = __builtin_amdgcn_mfma_f32_16x16x32_f16(aYl[ks], b0, acc[0], 0, 0, 0);
      half8 b0l = *(const half8*)&bbuf[buf][10 * 2 + ks][lane * 8];
      acc[0] = __builtin_amdgcn_mfma_f32_16x16x32_f16(aYh[ks], b0l, acc[0], 0, 0, 0);
#pragma unroll
      for (int k = 1; k < 10; ++k) {
        half8 ah = (k < 3) ? aF1[ks] : (k < 6) ? aF2[ks] : aF3[ks];
        half8 bh = *(const half8*)&bbuf[buf][k * 2 + ks][lane * 8];
        acc[k] = __builtin_amdgcn_mfma_f32_16x16x32_f16(ah, bh, acc[k], 0, 0, 0);
      }
    }
    // ---- Faa di Bruno + W3 on C-layout: lane holds (point=quad*4+r, j=nt*16+col) ----
    float b2v = b2[nt * 16 + col];
    float w3v = W3[nt * 16 + col];
#pragma unroll
    for (int r = 0; r < 4; ++r) {
      float z0 = acc[0][r] + b2v;
      float y2 = fast_tanh(z0);
      float g1 = fmaf(-y2, y2, 1.0f);
      float g2 = -2.0f * (y2 * g1);
      float g3 = g1 * fmaf(-6.0f, g1, 4.0f);
      float gp = acc[1][r], gt = acc[2][r];
      float gpp = acc[3][r], gpt = acc[4][r], gtt = acc[5][r];
      float zppp = acc[6][r], zppt = acc[7][r], zptt = acc[8][r], zttt = acc[9][r];
      float gp2 = gp * gp, gt2 = gt * gt;
      Tacc[0][r] = fmaf(w3v, g1 * gp, Tacc[0][r]);
      Tacc[1][r] = fmaf(w3v, g1 * gt, Tacc[1][r]);
      Tacc[2][r] = fmaf(w3v, fmaf(g2, gp2, g1 * gpp), Tacc[2][r]);
      Tacc[3][r] = fmaf(w3v, fmaf(g2, gp * gt, g1 * gpt), Tacc[3][r]);
      Tacc[4][r] = fmaf(w3v, fmaf(g2, gt2, g1 * gtt), Tacc[4][r]);
      Tacc[5][r] = fmaf(w3v, fmaf(g3, gp2 * gp, fmaf(3.0f * g2, gp * gpp, g1 * zppp)), Tacc[5][r]);
      Tacc[6][r] = fmaf(w3v, fmaf(g3, gp2 * gt, fmaf(g2, fmaf(2.0f, gp * gpt, gt * gpp), g1 * zppt)), Tacc[6][r]);
      Tacc[7][r] = fmaf(w3v, fmaf(g3, gp * gt2, fmaf(g2, fmaf(2.0f, gt * gpt, gp * gtt), g1 * zptt)), Tacc[7][r]);
      Tacc[8][r] = fmaf(w3v, fmaf(g3, gt2 * gt, fmaf(3.0f * g2, gt * gtt, g1 * zttt)), Tacc[8][r]);
    }

    // write the prefetched nt+1 frags into the other buffer, then barrier
    if (nt < 3) {
#pragma unroll
      for (int i = 0; i < 6; ++i) {
        int f = wave + 4 * i;
        if (f < 22) *(half8*)&bbuf[buf ^ 1][f][lane * 8] = pf[i];
      }
    }
    __syncthreads();
  }

  // ---- reduce over j: butterfly across the 16 cols (same quad group) ----
#pragma unroll
  for (int x = 0; x < 9; ++x) {
#pragma unroll
    for (int r = 0; r < 4; ++r) {
      float v = Tacc[x][r];
      v += __shfl_xor(v, 1, 16);
      v += __shfl_xor(v, 2, 16);
      v += __shfl_xor(v, 4, 16);
      v += __shfl_xor(v, 8, 16);
      Tacc[x][r] = v;
    }
  }

  // lane handles point = quad*4 + (col&3); lanes col<4 store.
  int rsel = col & 3;
  float T[9];
#pragma unroll
  for (int x = 0; x < 9; ++x) {
    float4v v = Tacc[x];
    T[x] = (rsel == 0) ? v[0] : (rsel == 1) ? v[1] : (rsel == 2) ? v[2] : v[3];
  }
  float Tp = T[0], Tt = T[1], Tpp = T[2], Tpt = T[3], Ttt = T[4];
  float Tppp = T[5], Tppt = T[6], Tptt = T[7], Tttt = T[8];

  int pi = min(pbase + quad * 4 + rsel, n - 1);
  float t2 = theta[pi];
  float s = sinf(t2), c = cosf(t2);
  float inv_s = 1.0f / s;
  float inv_s2 = inv_s * inv_s;

  float A = Tp * inv_s + Tt;          // u_theta
  float D = Tp * inv_s - Tt;          // u_phi
  float q1 = Tpt * inv_s - Tp * c * inv_s2;
  float A_t = q1 + Ttt;
  float D_t = q1 - Ttt;
  float q2 = Tptt * inv_s - 2.0f * Tpt * c * inv_s2
           + Tp * (s * s + 2.0f * c * c) * inv_s2 * inv_s;
  float A_tt = q2 + Tttt;
  float D_tt = q2 - Tttt;
  float A_pp = Tppp * inv_s + Tppt;
  float D_p  = Tpp * inv_s - Tpt;
  float D_pp = Tppp * inv_s - Tppt;

  float utt   = -(A_t * s + A * c);
  float uttt  = -(A_tt * s + 2.0f * A_t * c - A * s) * s + utt * c;
  float utpp  = -A_pp;
  float upht  = D_t * s + D * c;
  float uphtt = (D_tt * s + 2.0f * D_t * c - D * s) * s + upht * c;
  float upp   = D_p;
  float uppp  = D_pp;

  float r = radius[pi];
  float inv_r = 1.0f / r;
  float inv_r2 = inv_r * inv_r;
  float div_uh = (utt + upp) * inv_r * inv_s;
  float lap_t = s * inv_r2 * uttt + utpp * inv_s2 * inv_r2;
  float lap_p = s * inv_r2 * uphtt + uppp * inv_s2 * inv_r2;
  float comp = s * (lap_t * lap_t + lap_p * lap_p);
  float sv = -(A * hth[pi] + D * hph[pi]) - br[pi] * div_uh;
  float tg = div_uh - A * (s / c) * inv_r;

  if (col < 4 && pbase + quad * 4 + rsel < n) {
    out[pi]         = A;
    out[n + pi]     = D;
    out[2 * n + pi] = div_uh;
    out[3 * n + pi] = sv;
    out[4 * n + pi] = tg;
    out[5 * n + pi] = comp;
  }
}

extern "C" void kernel_launch(void* const* d_in, const int* in_sizes, int n_in,
                              void* d_out, int out_size, void* d_ws, size_t ws_size,
                              hipStream_t stream) {
  const float* phi    = (const float*)d_in[0];
  const float* theta  = (const float*)d_in[1];
  const float* radius = (const float*)d_in[2];
  const float* hth    = (const float*)d_in[3];
  const float* hph    = (const float*)d_in[4];
  const float* br     = (const float*)d_in[5];
  const float* W1     = (const float*)d_in[6];
  const float* b1     = (const float*)d_in[7];
  const float* W2     = (const float*)d_in[8];
  const float* b2     = (const float*)d_in[9];
  const float* W3     = (const float*)d_in[10];
  (void)ws_size; (void)n_in; (void)out_size;

  _Float16* Bws = (_Float16*)d_ws;     // 11 slots * 4 nt * 2 ks * 512 halfs = 88 KB
  float* out = (float*)d_out;
  int n = in_sizes[0];

  prep_B<<<(NH * NH + 255) / 256, 256, 0, stream>>>(W1, W2, Bws);
  int ntiles = (n + 15) / 16;
  int nblocks = (ntiles + 3) / 4;
  pinn_mfma<<<nblocks, 256, 0, stream>>>(
      phi, theta, radius, hth, hph, br, W1, b1, b2, W3, Bws, out, n);
}